// Round 4
// baseline (250.268 us; speedup 1.0000x reference)
//
#include <hip/hip_runtime.h>

#define NQ 22
#define DIMN (1u << NQ)

struct GenArg   { unsigned r[NQ]; unsigned frow[5]; };
struct MeasLArg { unsigned xm[11]; unsigned zm[11]; int gbit[11]; unsigned zrow[NQ]; };
struct MeasXArg { unsigned xm[11]; unsigned zm[11]; int gbit[11]; int qn[11]; };

// ---------------- prep: zero accumulators, compute cos/sin tables ----------------
// trig layout: trig[l*44 + b] = cos(theta[l][21-b]/2), trig[l*44 + 22 + b] = sin(...)
__global__ __launch_bounds__(256) void k_prep(const float* __restrict__ theta,
                                              float* __restrict__ acc,
                                              float* __restrict__ trig) {
    int t = threadIdx.x;
    acc[t] = 0.f;
    if (t < 2 * NQ) {
        int l = t / NQ, q = t % NQ, b = NQ - 1 - q;
        float h = 0.5f * theta[t];
        trig[l * 2 * NQ + b]      = cosf(h);
        trig[l * 2 * NQ + NQ + b] = sinf(h);
    }
}

// ------ generator: product-state formula at Linv*y + RY layer-2 bits 12..16 -------
__global__ __launch_bounds__(256) void k_gen(float* __restrict__ phi,
                                             const float* __restrict__ trig,
                                             GenArg G) {
    unsigned tid = blockIdx.x * 256u + threadIdx.x;        // [0, 2^17)
    unsigned base = (tid & 0xFFFu) | ((tid >> 12) << 17);
    float cv[NQ], sv[NQ];
#pragma unroll
    for (int b = 0; b < NQ; ++b) { cv[b] = trig[b]; sv[b] = trig[NQ + b]; }
    unsigned P0 = 0;
#pragma unroll
    for (int b = 0; b < NQ; ++b)
        P0 |= ((unsigned)__popc(base & G.r[b]) & 1u) << b;
    float c2[5], s2[5];
#pragma unroll
    for (int j = 0; j < 5; ++j) {
        c2[j] = trig[2 * NQ + 12 + j];
        s2[j] = trig[3 * NQ + 12 + j];
    }
    float v0[32], v1[32];
#pragma unroll
    for (int e = 0; e < 32; ++e) {
        unsigned F = 0;
        if (e & 1)  F ^= G.frow[0];
        if (e & 2)  F ^= G.frow[1];
        if (e & 4)  F ^= G.frow[2];
        if (e & 8)  F ^= G.frow[3];
        if (e & 16) F ^= G.frow[4];
        unsigned P = P0 ^ F;
        float prod = 1.f;
#pragma unroll
        for (int b = 1; b < NQ; ++b)
            prod *= ((P >> b) & 1u) ? sv[b] : cv[b];
        v0[e] = prod * ((P & 1u) ? sv[0] : cv[0]);
        v1[e] = prod * ((P & 1u) ? cv[0] : -sv[0]);
    }
#pragma unroll
    for (int j = 0; j < 5; ++j) {
#pragma unroll
        for (int e = 0; e < 32; ++e) {
            if (!(e & (1 << j))) {
                int e1 = e | (1 << j);
                float a0 = v0[e], a1 = v0[e1];
                v0[e]  = c2[j] * a0 - s2[j] * a1;
                v0[e1] = s2[j] * a0 + c2[j] * a1;
                float b0 = v1[e], b1 = v1[e1];
                v1[e]  = c2[j] * b0 - s2[j] * b1;
                v1[e1] = s2[j] * b0 + c2[j] * b1;
            }
        }
    }
#pragma unroll
    for (int e = 0; e < 32; ++e) {
        unsigned a = base | ((unsigned)e << 12);
        phi[a] = v0[e];
        phi[DIMN + a] = v1[e];
    }
}

// ---------------- RY layer 2 on 5 high bits [shift..shift+4], in registers -------
__global__ __launch_bounds__(256) void k_hi(float* __restrict__ phi,
                                            const float* __restrict__ trig,
                                            int shift) {
    unsigned tid = blockIdx.x * 256u + threadIdx.x;        // [0, 2^17)
    unsigned lowmask = (1u << shift) - 1u;
    unsigned base = (tid & lowmask) | ((tid >> shift) << (shift + 5));
    float c[5], s[5];
#pragma unroll
    for (int j = 0; j < 5; ++j) {
        c[j] = trig[2 * NQ + shift + j];
        s[j] = trig[3 * NQ + shift + j];
    }
    float v0[32], v1[32];
#pragma unroll
    for (int e = 0; e < 32; ++e) {
        unsigned a = base | ((unsigned)e << shift);
        v0[e] = phi[a];
        v1[e] = phi[DIMN + a];
    }
#pragma unroll
    for (int j = 0; j < 5; ++j) {
#pragma unroll
        for (int e = 0; e < 32; ++e) {
            if (!(e & (1 << j))) {
                int e1 = e | (1 << j);
                float a0 = v0[e], a1 = v0[e1];
                v0[e]  = c[j] * a0 - s[j] * a1;
                v0[e1] = s[j] * a0 + c[j] * a1;
                float b0 = v1[e], b1 = v1[e1];
                v1[e]  = c[j] * b0 - s[j] * b1;
                v1[e1] = s[j] * b0 + c[j] * b1;
            }
        }
    }
#pragma unroll
    for (int e = 0; e < 32; ++e) {
        unsigned a = base | ((unsigned)e << shift);
        phi[a] = v0[e];
        phi[DIMN + a] = v1[e];
    }
}

__device__ __forceinline__ float wave_sum(float v) {
    v += __shfl_down(v, 32); v += __shfl_down(v, 16); v += __shfl_down(v, 8);
    v += __shfl_down(v, 4);  v += __shfl_down(v, 2);  v += __shfl_down(v, 1);
    return v;
}
__device__ __forceinline__ float fflip(float v, unsigned sbit31) {
    return __int_as_float(__float_as_int(v) ^ (int)sbit31);
}
__device__ __forceinline__ unsigned ph4(unsigned g) { return g ^ ((g >> 6) & 3u); }

// ---- RY layer 2 bits 0..11 (register-staged) + low-mask X/Y + ALL Z measurements ----
__global__ __launch_bounds__(256) void k_low(float* __restrict__ phi,
                                             const float* __restrict__ trig,
                                             float* __restrict__ acc,
                                             MeasLArg M) {
    __shared__ float As[4096];
    __shared__ float Bs[4096];
    __shared__ float red[4 * 44];
    float4* As4 = (float4*)As;
    float4* Bs4 = (float4*)Bs;
    int t = threadIdx.x;
    unsigned base = blockIdx.x * 4096u;
    float a[16], b[16];

    // ---- phase 0: global load (16 consecutive elems/thread), gates bits 0..3 ----
    {
        const float4* g0 = (const float4*)(phi + base);
        const float4* g1 = (const float4*)(phi + DIMN + base);
#pragma unroll
        for (int k = 0; k < 4; ++k) {
            float4 va = g0[4 * t + k];
            a[4 * k] = va.x; a[4 * k + 1] = va.y; a[4 * k + 2] = va.z; a[4 * k + 3] = va.w;
            float4 vb = g1[4 * t + k];
            b[4 * k] = vb.x; b[4 * k + 1] = vb.y; b[4 * k + 2] = vb.z; b[4 * k + 3] = vb.w;
        }
#pragma unroll
        for (int g = 0; g < 4; ++g) {
            float c = trig[2 * NQ + g], s = trig[3 * NQ + g];
#pragma unroll
            for (int e = 0; e < 16; ++e) {
                if (!(e & (1 << g))) {
                    int e1 = e | (1 << g);
                    float x0 = a[e], x1 = a[e1];
                    a[e] = c * x0 - s * x1; a[e1] = s * x0 + c * x1;
                    float y0 = b[e], y1 = b[e1];
                    b[e] = c * y0 - s * y1; b[e1] = s * y0 + c * y1;
                }
            }
        }
        unsigned sw = (unsigned)(t >> 4) & 3u;
#pragma unroll
        for (int k = 0; k < 4; ++k) {
            unsigned f = ((unsigned)(4 * t + k)) ^ sw;
            As4[f] = make_float4(a[4 * k], a[4 * k + 1], a[4 * k + 2], a[4 * k + 3]);
            Bs4[f] = make_float4(b[4 * k], b[4 * k + 1], b[4 * k + 2], b[4 * k + 3]);
        }
    }
    __syncthreads();

    // ---- phase 1: exchange to bits 4..7 ownership, gates bits 4..7 ----
    {
        unsigned lo = (unsigned)t & 15u, hi = (unsigned)t >> 4;
        unsigned swz = (hi & 3u) << 2;
#pragma unroll
        for (int j = 0; j < 16; ++j) {
            unsigned i = lo | ((unsigned)j << 4) | (hi << 8);
            a[j] = As[i ^ swz];
            b[j] = Bs[i ^ swz];
        }
#pragma unroll
        for (int g = 0; g < 4; ++g) {
            float c = trig[2 * NQ + 4 + g], s = trig[3 * NQ + 4 + g];
#pragma unroll
            for (int e = 0; e < 16; ++e) {
                if (!(e & (1 << g))) {
                    int e1 = e | (1 << g);
                    float x0 = a[e], x1 = a[e1];
                    a[e] = c * x0 - s * x1; a[e1] = s * x0 + c * x1;
                    float y0 = b[e], y1 = b[e1];
                    b[e] = c * y0 - s * y1; b[e1] = s * y0 + c * y1;
                }
            }
        }
#pragma unroll
        for (int j = 0; j < 16; ++j) {
            unsigned i = lo | ((unsigned)j << 4) | (hi << 8);
            As[i ^ swz] = a[j];
            Bs[i ^ swz] = b[j];
        }
    }
    __syncthreads();

    // ---- phase 2: exchange to bits 8..11 ownership, gates bits 8..11, write out ----
    {
#pragma unroll
        for (int j = 0; j < 16; ++j) {
            unsigned i = (unsigned)t | ((unsigned)j << 8);
            unsigned p = i ^ (((unsigned)j & 3u) << 2);
            a[j] = As[p];
            b[j] = Bs[p];
        }
#pragma unroll
        for (int g = 0; g < 4; ++g) {
            float c = trig[2 * NQ + 8 + g], s = trig[3 * NQ + 8 + g];
#pragma unroll
            for (int e = 0; e < 16; ++e) {
                if (!(e & (1 << g))) {
                    int e1 = e | (1 << g);
                    float x0 = a[e], x1 = a[e1];
                    a[e] = c * x0 - s * x1; a[e1] = s * x0 + c * x1;
                    float y0 = b[e], y1 = b[e1];
                    b[e] = c * y0 - s * y1; b[e1] = s * y0 + c * y1;
                }
            }
        }
#pragma unroll
        for (int j = 0; j < 16; ++j) {
            unsigned i = (unsigned)t | ((unsigned)j << 8);
            phi[base + i] = a[j];
            phi[DIMN + base + i] = b[j];
            unsigned p = i ^ (((unsigned)j & 3u) << 2);
            As[p] = a[j];
            Bs[p] = b[j];
        }
    }

    // ---- fused Z measurement from final registers a[],b[] ----
    // element index i = t | (j<<8); sign for q>=10: parity(i >> (21-q)); q=1..9 block-const.
    // j-tree: suffix-parity sign structure over j bits (i bits 8..11).
    float SSv[3], z0v[3], z1v[3], z2v[3], z3v[3], d4v[3];
    {
        unsigned Wt = (unsigned)t;          // suffix parities of t (bits 0..7)
        Wt ^= Wt >> 1; Wt ^= Wt >> 2; Wt ^= Wt >> 4;
        (void)Wt;
#pragma unroll
        for (int c = 0; c < 3; ++c) {
            float p[16];
#pragma unroll
            for (int j = 0; j < 16; ++j)
                p[j] = (c == 0) ? a[j] * a[j] : (c == 1) ? b[j] * b[j] : a[j] * b[j];
            float s1[8], d1[8];
#pragma unroll
            for (int j = 0; j < 8; ++j) { s1[j] = p[j] + p[j + 8]; d1[j] = p[j] - p[j + 8]; }
            float s2[4], d2[4];
#pragma unroll
            for (int j = 0; j < 4; ++j) { s2[j] = s1[j] + s1[j + 4]; d2[j] = d1[j] - d1[j + 4]; }
            float d3a = d2[0] - d2[2], d3b = d2[1] - d2[3];
            SSv[c] = (s2[0] + s2[1]) + (s2[2] + s2[3]);
            z0v[c] = ((d1[0] + d1[1]) + (d1[2] + d1[3])) + ((d1[4] + d1[5]) + (d1[6] + d1[7]));
            z1v[c] = (d2[0] + d2[1]) + (d2[2] + d2[3]);
            z2v[c] = d3a + d3b;
            d4v[c] = d3a - d3b;
        }
    }
    // wave-reduce 39 values: idx 0..2 = SS, 3+3k+c = zt_k (k=0..11); zt4..11 = +/- d4
    {
        unsigned Wt = (unsigned)t;
        Wt ^= Wt >> 1; Wt ^= Wt >> 2; Wt ^= Wt >> 4;
        int lane = t & 63, w = t >> 6;
#pragma unroll
        for (int c = 0; c < 3; ++c) {
            float v;
            v = wave_sum(SSv[c]); if (lane == 0) red[w * 39 + c] = v;
            v = wave_sum(z0v[c]); if (lane == 0) red[w * 39 + 3 + c] = v;
            v = wave_sum(z1v[c]); if (lane == 0) red[w * 39 + 6 + c] = v;
            v = wave_sum(z2v[c]); if (lane == 0) red[w * 39 + 9 + c] = v;
            v = wave_sum(z3v[c] = d4v[c]); if (lane == 0) red[w * 39 + 12 + c] = v;
#pragma unroll
            for (int k = 4; k < 12; ++k) {
                unsigned sb = ((Wt >> (11 - k)) & 1u) << 31;
                v = wave_sum(fflip(d4v[c], sb));
                if (lane == 0) red[w * 39 + 3 + 3 * k + c] = v;
            }
        }
    }
    __syncthreads();
    if (t < 66) {
        int c = t % 3, q = t / 3;
        int slot = (q == 0 || q == 21) ? (3 + 33 + c) : (q < 10 ? c : 3 + 3 * (q - 10) + c);
        float val = red[slot] + red[39 + slot] + red[78 + slot] + red[117 + slot];
        unsigned sg = (unsigned)__popc(base & M.zrow[q]) & 1u;
        atomicAdd(&acc[4 * NQ + 3 * q + c], sg ? -val : val);
    }
    __syncthreads();

    // ---- measurements q10..20 (masks within bits 0..11), vectorized from LDS ----
    int lane = t & 63, w = t >> 6;
    for (int i = 0; i < 11; ++i) {
        unsigned m = M.xm[i], zm = M.zm[i];
        unsigned zb = (unsigned)__popc(base & zm) & 1u;
        float t00 = 0.f, t11 = 0.f, t01 = 0.f, u01 = 0.f;
        if (i < 10) {
            int gb = M.gbit[i];
            unsigned mg4 = m >> 2;
            unsigned swap2 = m & 3u;            // 0 or 2
#pragma unroll
            for (int r = 0; r < 2; ++r) {
                unsigned gc = (unsigned)t + 256u * r;
                unsigned g = ((gc >> gb) << (gb + 1)) | (gc & ((1u << gb) - 1u));
                unsigned gx = g ^ mg4;
                float4 a0 = As4[ph4(g)],  a1 = Bs4[ph4(g)];
                float4 b0 = As4[ph4(gx)], b1 = Bs4[ph4(gx)];
                if (swap2) {
                    b0 = make_float4(b0.z, b0.w, b0.x, b0.y);
                    b1 = make_float4(b1.z, b1.w, b1.x, b1.y);
                }
                unsigned szg = ((unsigned)__popc((g << 2) & zm) + zb) & 1u;
                unsigned szx = ((unsigned)__popc((gx << 2) & zm) + zb) & 1u;
                unsigned fg = szg << 31, fx = szx << 31;
                const float* A0 = &a0.x; const float* A1 = &a1.x;
                const float* B0 = &b0.x; const float* B1 = &b1.x;
#pragma unroll
                for (int j = 0; j < 4; ++j) {
                    t00 += A0[j] * B0[j];
                    t11 += A1[j] * B1[j];
                    float p = A0[j] * B1[j], r2 = B0[j] * A1[j];
                    t01 += p + r2;
                    u01 += fflip(p, fx) + fflip(r2, fg);
                }
            }
            t00 *= 2.f; t11 *= 2.f;
        } else {
            // q20: m = 3, partner within float4
#pragma unroll
            for (int k = 0; k < 4; ++k) {
                unsigned g = (unsigned)t + 256u * k;
                float4 a0 = As4[ph4(g)], a1 = Bs4[ph4(g)];
                unsigned szg = ((unsigned)__popc((g << 2) & zm) + zb) & 1u;
                const float* A0 = &a0.x; const float* A1 = &a1.x;
#pragma unroll
                for (int j = 0; j < 4; ++j) {
                    int jx = j ^ 3;
                    float p = A0[j] * A0[jx];
                    float q2 = A1[j] * A1[jx];
                    float cr = A0[j] * A1[jx];
                    t00 += p; t11 += q2; t01 += cr;
                    unsigned sj = ((unsigned)(jx >> 1) & 1u) ^ szg;   // zm&3 == 2
                    u01 += fflip(cr, sj << 31);
                }
            }
        }
        float vals[4] = { t00, t11, t01, u01 };
#pragma unroll
        for (int j = 0; j < 4; ++j) {
            float v = wave_sum(vals[j]);
            if (lane == 0) red[w * 44 + 4 * i + j] = v;
        }
    }
    __syncthreads();
    if (t < 44) {
        float r = red[t] + red[44 + t] + red[88 + t] + red[132 + t];
        atomicAdd(&acc[40 + t], r);
    }
}

// ------- coalesced X/Y measurements for high masks (q0..9, q21), grid (1024,11) ------
__global__ __launch_bounds__(256) void k_measX(const float* __restrict__ phi,
                                               float* __restrict__ acc,
                                               MeasXArg M) {
    __shared__ float red[16];
    int t = threadIdx.x;
    int slice = blockIdx.y;
    unsigned m = M.xm[slice], zm = M.zm[slice];
    int gb = M.gbit[slice];
    unsigned mg4 = m >> 2;
    unsigned ml2 = m & 3u;                      // 0 or 1
    unsigned zl = zm & 3u;
    unsigned pg31[4], px31[4];
#pragma unroll
    for (int j = 0; j < 4; ++j) {
        pg31[j] = (((unsigned)__popc((unsigned)j & zl) & 1u) << 31);
        px31[j] = (((unsigned)__popc(((unsigned)j ^ ml2) & zl) & 1u) << 31);
    }
    unsigned tid = blockIdx.x * 256u + (unsigned)t;   // [0, 262144)
    const float4* p0 = (const float4*)phi;
    const float4* p1 = (const float4*)(phi + DIMN);
    float t00 = 0.f, t11 = 0.f, t01 = 0.f, u01 = 0.f;
#pragma unroll
    for (int it = 0; it < 2; ++it) {
        unsigned gc = tid + (unsigned)it * 262144u;   // [0, 2^19)
        unsigned g = ((gc >> gb) << (gb + 1)) | (gc & ((1u << gb) - 1u));
        unsigned gx = g ^ mg4;
        float4 a0 = p0[g], a1 = p1[g];
        float4 b0 = p0[gx], b1 = p1[gx];
        if (ml2) {
            b0 = make_float4(b0.y, b0.x, b0.w, b0.z);
            b1 = make_float4(b1.y, b1.x, b1.w, b1.z);
        }
        unsigned fg = (((unsigned)__popc((g << 2) & zm) & 1u) << 31);
        unsigned fx = (((unsigned)__popc((gx << 2) & zm) & 1u) << 31);
        const float* A0 = &a0.x; const float* A1 = &a1.x;
        const float* B0 = &b0.x; const float* B1 = &b1.x;
#pragma unroll
        for (int j = 0; j < 4; ++j) {
            t00 += A0[j] * B0[j];
            t11 += A1[j] * B1[j];
            float p = A0[j] * B1[j], r = B0[j] * A1[j];
            t01 += p + r;
            u01 += fflip(p, fx ^ px31[j]) + fflip(r, fg ^ pg31[j]);
        }
    }
    t00 *= 2.f; t11 *= 2.f;
    int lane = t & 63, w = t >> 6;
    float vals[4] = { t00, t11, t01, u01 };
#pragma unroll
    for (int j = 0; j < 4; ++j) {
        float v = wave_sum(vals[j]);
        if (lane == 0) red[w * 4 + j] = v;
    }
    __syncthreads();
    if (t < 4) {
        float r = red[t] + red[4 + t] + red[8 + t] + red[12 + t];
        atomicAdd(&acc[4 * M.qn[slice] + t], r);
    }
}

// ---------------- finalize: combine 154 sums into the scalar loss ----------------
__global__ __launch_bounds__(64) void k_final(const float* __restrict__ acc,
                                              float* __restrict__ out) {
    int t = threadIdx.x;
    float v = 0.f;
    if (t < NQ) {
        float t00 = acc[4 * t], t11 = acc[4 * t + 1];
        float t01 = acc[4 * t + 2], u01 = acc[4 * t + 3];
        float d = t00 - t11;
        v = 0.5f * d * d + 2.f * t01 * t01 + 2.f * u01 * u01;   // X op + Y op
    } else if (t < 2 * NQ) {
        int q = t - NQ;
        float z0 = acc[4 * NQ + 3 * q], z1 = acc[4 * NQ + 3 * q + 1];
        float zz = acc[4 * NQ + 3 * q + 2];
        float d = z0 - z1;
        v = 0.5f * d * d + 2.f * zz * zz;                       // Z op
    }
    v += __shfl_down(v, 32); v += __shfl_down(v, 16); v += __shfl_down(v, 8);
    v += __shfl_down(v, 4);  v += __shfl_down(v, 2);  v += __shfl_down(v, 1);
    if (t == 0) out[0] = v;
}

extern "C" void kernel_launch(void* const* d_in, const int* in_sizes, int n_in,
                              void* d_out, int out_size, void* d_ws, size_t ws_size,
                              hipStream_t stream) {
    const float* theta = (const float*)d_in[0];
    float* out  = (float*)d_out;
    float* ws   = (float*)d_ws;
    float* phi  = ws;                          // 2 * DIMN floats (32 MB)
    float* acc  = ws + 2 * (size_t)DIMN;       // 256 floats
    float* trig = acc + 256;                   // 88 floats

    // Build L (one CNOT ring layer over GF(2)); qubit q lives at bit (21-q).
    unsigned L[NQ];
    for (int b = 0; b < NQ; ++b) L[b] = 1u << b;
    for (int q = 0; q < NQ; ++q) {
        int bc = NQ - 1 - q;
        int bt = NQ - 1 - ((q + 1) % NQ);
        L[bt] ^= L[bc];
    }
    // Invert over GF(2): x_b = parity(y & Linv[b])
    unsigned mat[NQ], aug[NQ];
    for (int b = 0; b < NQ; ++b) { mat[b] = L[b]; aug[b] = 1u << b; }
    for (int col = 0; col < NQ; ++col) {
        int piv = col;
        while (!((mat[piv] >> col) & 1u)) ++piv;
        unsigned tm = mat[piv]; mat[piv] = mat[col]; mat[col] = tm;
        unsigned ta = aug[piv]; aug[piv] = aug[col]; aug[col] = ta;
        for (int r = 0; r < NQ; ++r)
            if (r != col && ((mat[r] >> col) & 1u)) { mat[r] ^= mat[col]; aug[r] ^= aug[col]; }
    }
    GenArg ga;
    for (int b = 0; b < NQ; ++b) ga.r[b] = aug[b];
    for (int j = 0; j < 5; ++j) {
        unsigned f = 0;
        for (int r = 0; r < NQ; ++r)
            if ((aug[r] >> (12 + j)) & 1u) f |= 1u << r;
        ga.frow[j] = f;
    }

    // Conjugated Pauli masks: X_q -> X^(col 21-q of Linv); Z_q -> Z^(row 21-q of L)
    unsigned xmask[NQ], zmask[NQ];
    for (int j = 0; j < NQ; ++j) {
        int b = NQ - 1 - j;
        unsigned xm = 0;
        for (int r = 0; r < NQ; ++r)
            if ((aug[r] >> b) & 1u) xm |= 1u << r;
        xmask[j] = xm;          // q0..9: bit-pairs {21-j,20-j}; q10..20: low pairs; q21: {0,20,21}
        zmask[j] = L[b];        // suffix masks
    }
    auto topbit = [](unsigned v) { int b = 0; while (v >> (b + 1)) ++b; return b; };

    MeasLArg ml;
    for (int i = 0; i < 11; ++i) {
        int q = 10 + i;
        ml.xm[i] = xmask[q]; ml.zm[i] = zmask[q];
        ml.gbit[i] = topbit(xmask[q]) - 2;     // q10..19 (q20 special-cased)
    }
    for (int q = 0; q < NQ; ++q) ml.zrow[q] = zmask[q];
    MeasXArg mx;
    for (int i = 0; i < 11; ++i) {
        int q = (i < 10) ? i : 21;
        mx.xm[i] = xmask[q]; mx.zm[i] = zmask[q];
        mx.gbit[i] = topbit(xmask[q]) - 2;
        mx.qn[i] = q;
    }

    k_prep<<<1, 256, 0, stream>>>(theta, acc, trig);
    k_gen<<<512, 256, 0, stream>>>(phi, trig, ga);
    k_hi<<<512, 256, 0, stream>>>(phi, trig, 17);
    k_low<<<1024, 256, 0, stream>>>(phi, trig, acc, ml);
    k_measX<<<dim3(1024, 11), 256, 0, stream>>>(phi, acc, mx);
    k_final<<<1, 64, 0, stream>>>(acc, out);
}

// Round 5
// 196.938 us; speedup vs baseline: 1.2708x; 1.2708x over previous
//
#include <hip/hip_runtime.h>

#define NQ 22
#define DIMN (1u << NQ)

struct GenArg   { unsigned r[NQ]; unsigned frow[5]; };
struct HiMArg   { unsigned he[6]; unsigned hm[6]; unsigned zme[6]; unsigned zmm[6]; };
struct MeasLArg { unsigned xm[11]; unsigned zm[11]; int gbit[11]; unsigned zrow[NQ]; };
struct Meas5Arg { unsigned xm[5]; unsigned zm[5]; int gbit[5]; int qn[5]; };

// ---------------- prep: zero accumulators, compute cos/sin tables ----------------
// trig layout: trig[l*44 + b] = cos(theta[l][21-b]/2), trig[l*44 + 22 + b] = sin(...)
__global__ __launch_bounds__(256) void k_prep(const float* __restrict__ theta,
                                              float* __restrict__ acc,
                                              float* __restrict__ trig) {
    int t = threadIdx.x;
    acc[t] = 0.f;
    if (t < 2 * NQ) {
        int l = t / NQ, q = t % NQ, b = NQ - 1 - q;
        float h = 0.5f * theta[t];
        trig[l * 2 * NQ + b]      = cosf(h);
        trig[l * 2 * NQ + NQ + b] = sinf(h);
    }
}

// ------ generator: product-state formula at Linv*y + RY layer-2 bits 12..16 -------
__global__ __launch_bounds__(256) void k_gen(float* __restrict__ phi,
                                             const float* __restrict__ trig,
                                             GenArg G) {
    unsigned tid = blockIdx.x * 256u + threadIdx.x;        // [0, 2^17)
    unsigned base = (tid & 0xFFFu) | ((tid >> 12) << 17);
    float cv[NQ], sv[NQ];
#pragma unroll
    for (int b = 0; b < NQ; ++b) { cv[b] = trig[b]; sv[b] = trig[NQ + b]; }
    unsigned P0 = 0;
#pragma unroll
    for (int b = 0; b < NQ; ++b)
        P0 |= ((unsigned)__popc(base & G.r[b]) & 1u) << b;
    float c2[5], s2[5];
#pragma unroll
    for (int j = 0; j < 5; ++j) {
        c2[j] = trig[2 * NQ + 12 + j];
        s2[j] = trig[3 * NQ + 12 + j];
    }
    float v0[32], v1[32];
#pragma unroll
    for (int e = 0; e < 32; ++e) {
        unsigned F = 0;
        if (e & 1)  F ^= G.frow[0];
        if (e & 2)  F ^= G.frow[1];
        if (e & 4)  F ^= G.frow[2];
        if (e & 8)  F ^= G.frow[3];
        if (e & 16) F ^= G.frow[4];
        unsigned P = P0 ^ F;
        float prod = 1.f;
#pragma unroll
        for (int b = 1; b < NQ; ++b)
            prod *= ((P >> b) & 1u) ? sv[b] : cv[b];
        v0[e] = prod * ((P & 1u) ? sv[0] : cv[0]);
        v1[e] = prod * ((P & 1u) ? cv[0] : -sv[0]);
    }
#pragma unroll
    for (int j = 0; j < 5; ++j) {
#pragma unroll
        for (int e = 0; e < 32; ++e) {
            if (!(e & (1 << j))) {
                int e1 = e | (1 << j);
                float a0 = v0[e], a1 = v0[e1];
                v0[e]  = c2[j] * a0 - s2[j] * a1;
                v0[e1] = s2[j] * a0 + c2[j] * a1;
                float b0 = v1[e], b1 = v1[e1];
                v1[e]  = c2[j] * b0 - s2[j] * b1;
                v1[e1] = s2[j] * b0 + c2[j] * b1;
            }
        }
    }
#pragma unroll
    for (int e = 0; e < 32; ++e) {
        unsigned a = base | ((unsigned)e << 12);
        phi[a] = v0[e];
        phi[DIMN + a] = v1[e];
    }
}

__device__ __forceinline__ float wave_sum(float v) {
    v += __shfl_down(v, 32); v += __shfl_down(v, 16); v += __shfl_down(v, 8);
    v += __shfl_down(v, 4);  v += __shfl_down(v, 2);  v += __shfl_down(v, 1);
    return v;
}
__device__ __forceinline__ float fflip(float v, unsigned sbit31) {
    return __int_as_float(__float_as_int(v) ^ (int)sbit31);
}
__device__ __forceinline__ unsigned ph4(unsigned g) { return g ^ ((g >> 6) & 3u); }

// ---- RY layer 2 on bits 17..21 + fused X/Y measurements for q1..q6 ----
// lane = y bits 0..5; wave m = y bits 14..16; blockIdx = y bits 6..13; regs e = bits 17..21.
// q1..q3: xmask in bits 17..21 -> register pairing.  q4..q6: xmask spans bits 14..17 ->
// LDS exchange across waves.  zmasks all >= bit 14 -> commute with later low-bit gates.
__global__ __launch_bounds__(512) void k_hiM(float* __restrict__ phi,
                                             const float* __restrict__ trig,
                                             float* __restrict__ acc,
                                             HiMArg H) {
    __shared__ float S0[8 * 8 * 64];
    __shared__ float S1[8 * 8 * 64];
    __shared__ float red[8 * 24];
    int t = threadIdx.x;
    int l = t & 63, m = t >> 6;                      // m in [0,8) = y bits 14..16
    unsigned base = (unsigned)l | (blockIdx.x << 6) | ((unsigned)m << 14);
    float c[5], s[5];
#pragma unroll
    for (int j = 0; j < 5; ++j) {
        c[j] = trig[2 * NQ + 17 + j];
        s[j] = trig[3 * NQ + 17 + j];
    }
    float v0[32], v1[32];
#pragma unroll
    for (int e = 0; e < 32; ++e) {
        unsigned a = base | ((unsigned)e << 17);
        v0[e] = phi[a];
        v1[e] = phi[DIMN + a];
    }
#pragma unroll
    for (int j = 0; j < 5; ++j) {
#pragma unroll
        for (int e = 0; e < 32; ++e) {
            if (!(e & (1 << j))) {
                int e1 = e | (1 << j);
                float a0 = v0[e], a1 = v0[e1];
                v0[e]  = c[j] * a0 - s[j] * a1;
                v0[e1] = s[j] * a0 + c[j] * a1;
                float b0 = v1[e], b1 = v1[e1];
                v1[e]  = c[j] * b0 - s[j] * b1;
                v1[e1] = s[j] * b0 + c[j] * b1;
            }
        }
    }
#pragma unroll
    for (int e = 0; e < 32; ++e) {
        unsigned a = base | ((unsigned)e << 17);
        phi[a] = v0[e];
        phi[DIMN + a] = v1[e];
    }

    float t00[6], t11[6], t01[6], u01[6];
#pragma unroll
    for (int i = 0; i < 6; ++i) { t00[i] = 0.f; t11[i] = 0.f; t01[i] = 0.f; u01[i] = 0.f; }

    // ---- part A: register masks (q1..q3) ----
#pragma unroll
    for (int i = 0; i < 3; ++i) {
        unsigned ex = H.he[i], zme = H.zme[i];
#pragma unroll
        for (int e = 0; e < 32; ++e) {
            int ep = (int)((unsigned)e ^ ex);
            t00[i] += v0[e] * v0[ep];
            t11[i] += v1[e] * v1[ep];
            float p = v0[e] * v1[ep];
            t01[i] += p;
            unsigned sg = ((unsigned)__popc((unsigned)ep & zme) & 1u) << 31;
            u01[i] += fflip(p, sg);
        }
    }

    // ---- part B: cross-wave masks (q4..q6) via LDS, chunks of 8 elements ----
    unsigned msgn[3];
#pragma unroll
    for (int i = 0; i < 3; ++i)
        msgn[i] = ((unsigned)__popc(((unsigned)m ^ H.hm[3 + i]) & H.zmm[3 + i]) & 1u) << 31;
#pragma unroll
    for (int cch = 0; cch < 4; ++cch) {
#pragma unroll
        for (int j = 0; j < 8; ++j) {
            S0[(j * 8 + m) * 64 + l] = v0[8 * cch + j];
            S1[(j * 8 + m) * 64 + l] = v1[8 * cch + j];
        }
        __syncthreads();
#pragma unroll
        for (int i = 0; i < 3; ++i) {
            int mp = (int)((unsigned)m ^ H.hm[3 + i]);
            unsigned ex = H.he[3 + i], zme = H.zme[3 + i];
#pragma unroll
            for (int j = 0; j < 8; ++j) {
                int jp = (int)((unsigned)j ^ ex);
                float p0 = S0[(jp * 8 + mp) * 64 + l];
                float p1 = S1[(jp * 8 + mp) * 64 + l];
                t00[3 + i] += v0[8 * cch + j] * p0;
                t11[3 + i] += v1[8 * cch + j] * p1;
                float p = v0[8 * cch + j] * p1;
                t01[3 + i] += p;
                unsigned es = ((unsigned)__popc((unsigned)(8 * cch + jp) & zme) & 1u) << 31;
                u01[3 + i] += fflip(p, es ^ msgn[i]);
            }
        }
        __syncthreads();
    }

    // ---- block reduce: 6 masks x 4 values, 8 waves ----
    int lane = t & 63, w = t >> 6;
#pragma unroll
    for (int i = 0; i < 6; ++i) {
        float vals[4] = { t00[i], t11[i], t01[i], u01[i] };
#pragma unroll
        for (int j = 0; j < 4; ++j) {
            float v = wave_sum(vals[j]);
            if (lane == 0) red[w * 24 + i * 4 + j] = v;
        }
    }
    __syncthreads();
    if (t < 24) {
        float r = 0.f;
#pragma unroll
        for (int w2 = 0; w2 < 8; ++w2) r += red[w2 * 24 + t];
        int q = 1 + (t >> 2);                       // qubits 1..6
        atomicAdd(&acc[4 * q + (t & 3)], r);
    }
}

// ---- RY layer 2 bits 0..11 (register-staged) + low-mask X/Y + ALL Z measurements ----
__global__ __launch_bounds__(256) void k_low(float* __restrict__ phi,
                                             const float* __restrict__ trig,
                                             float* __restrict__ acc,
                                             MeasLArg M) {
    __shared__ float As[4096];
    __shared__ float Bs[4096];
    __shared__ float red[4 * 44];
    float4* As4 = (float4*)As;
    float4* Bs4 = (float4*)Bs;
    int t = threadIdx.x;
    unsigned base = blockIdx.x * 4096u;
    float a[16], b[16];

    // ---- phase 0: global load (16 consecutive elems/thread), gates bits 0..3 ----
    {
        const float4* g0 = (const float4*)(phi + base);
        const float4* g1 = (const float4*)(phi + DIMN + base);
#pragma unroll
        for (int k = 0; k < 4; ++k) {
            float4 va = g0[4 * t + k];
            a[4 * k] = va.x; a[4 * k + 1] = va.y; a[4 * k + 2] = va.z; a[4 * k + 3] = va.w;
            float4 vb = g1[4 * t + k];
            b[4 * k] = vb.x; b[4 * k + 1] = vb.y; b[4 * k + 2] = vb.z; b[4 * k + 3] = vb.w;
        }
#pragma unroll
        for (int g = 0; g < 4; ++g) {
            float c = trig[2 * NQ + g], s = trig[3 * NQ + g];
#pragma unroll
            for (int e = 0; e < 16; ++e) {
                if (!(e & (1 << g))) {
                    int e1 = e | (1 << g);
                    float x0 = a[e], x1 = a[e1];
                    a[e] = c * x0 - s * x1; a[e1] = s * x0 + c * x1;
                    float y0 = b[e], y1 = b[e1];
                    b[e] = c * y0 - s * y1; b[e1] = s * y0 + c * y1;
                }
            }
        }
        unsigned sw = (unsigned)(t >> 4) & 3u;
#pragma unroll
        for (int k = 0; k < 4; ++k) {
            unsigned f = ((unsigned)(4 * t + k)) ^ sw;
            As4[f] = make_float4(a[4 * k], a[4 * k + 1], a[4 * k + 2], a[4 * k + 3]);
            Bs4[f] = make_float4(b[4 * k], b[4 * k + 1], b[4 * k + 2], b[4 * k + 3]);
        }
    }
    __syncthreads();

    // ---- phase 1: exchange to bits 4..7 ownership, gates bits 4..7 ----
    {
        unsigned lo = (unsigned)t & 15u, hi = (unsigned)t >> 4;
        unsigned swz = (hi & 3u) << 2;
#pragma unroll
        for (int j = 0; j < 16; ++j) {
            unsigned i = lo | ((unsigned)j << 4) | (hi << 8);
            a[j] = As[i ^ swz];
            b[j] = Bs[i ^ swz];
        }
#pragma unroll
        for (int g = 0; g < 4; ++g) {
            float c = trig[2 * NQ + 4 + g], s = trig[3 * NQ + 4 + g];
#pragma unroll
            for (int e = 0; e < 16; ++e) {
                if (!(e & (1 << g))) {
                    int e1 = e | (1 << g);
                    float x0 = a[e], x1 = a[e1];
                    a[e] = c * x0 - s * x1; a[e1] = s * x0 + c * x1;
                    float y0 = b[e], y1 = b[e1];
                    b[e] = c * y0 - s * y1; b[e1] = s * y0 + c * y1;
                }
            }
        }
#pragma unroll
        for (int j = 0; j < 16; ++j) {
            unsigned i = lo | ((unsigned)j << 4) | (hi << 8);
            As[i ^ swz] = a[j];
            Bs[i ^ swz] = b[j];
        }
    }
    __syncthreads();

    // ---- phase 2: exchange to bits 8..11 ownership, gates bits 8..11, write out ----
    {
#pragma unroll
        for (int j = 0; j < 16; ++j) {
            unsigned i = (unsigned)t | ((unsigned)j << 8);
            unsigned p = i ^ (((unsigned)j & 3u) << 2);
            a[j] = As[p];
            b[j] = Bs[p];
        }
#pragma unroll
        for (int g = 0; g < 4; ++g) {
            float c = trig[2 * NQ + 8 + g], s = trig[3 * NQ + 8 + g];
#pragma unroll
            for (int e = 0; e < 16; ++e) {
                if (!(e & (1 << g))) {
                    int e1 = e | (1 << g);
                    float x0 = a[e], x1 = a[e1];
                    a[e] = c * x0 - s * x1; a[e1] = s * x0 + c * x1;
                    float y0 = b[e], y1 = b[e1];
                    b[e] = c * y0 - s * y1; b[e1] = s * y0 + c * y1;
                }
            }
        }
#pragma unroll
        for (int j = 0; j < 16; ++j) {
            unsigned i = (unsigned)t | ((unsigned)j << 8);
            phi[base + i] = a[j];
            phi[DIMN + base + i] = b[j];
            unsigned p = i ^ (((unsigned)j & 3u) << 2);
            As[p] = a[j];
            Bs[p] = b[j];
        }
    }

    // ---- fused Z measurement from final registers a[],b[] ----
    float SSv[3], z0v[3], z1v[3], z2v[3], d4v[3];
    {
#pragma unroll
        for (int c = 0; c < 3; ++c) {
            float p[16];
#pragma unroll
            for (int j = 0; j < 16; ++j)
                p[j] = (c == 0) ? a[j] * a[j] : (c == 1) ? b[j] * b[j] : a[j] * b[j];
            float s1[8], d1[8];
#pragma unroll
            for (int j = 0; j < 8; ++j) { s1[j] = p[j] + p[j + 8]; d1[j] = p[j] - p[j + 8]; }
            float s2[4], d2[4];
#pragma unroll
            for (int j = 0; j < 4; ++j) { s2[j] = s1[j] + s1[j + 4]; d2[j] = d1[j] - d1[j + 4]; }
            float d3a = d2[0] - d2[2], d3b = d2[1] - d2[3];
            SSv[c] = (s2[0] + s2[1]) + (s2[2] + s2[3]);
            z0v[c] = ((d1[0] + d1[1]) + (d1[2] + d1[3])) + ((d1[4] + d1[5]) + (d1[6] + d1[7]));
            z1v[c] = (d2[0] + d2[1]) + (d2[2] + d2[3]);
            z2v[c] = d3a + d3b;
            d4v[c] = d3a - d3b;
        }
    }
    {
        unsigned Wt = (unsigned)t;
        Wt ^= Wt >> 1; Wt ^= Wt >> 2; Wt ^= Wt >> 4;
        int lane = t & 63, w = t >> 6;
#pragma unroll
        for (int c = 0; c < 3; ++c) {
            float v;
            v = wave_sum(SSv[c]); if (lane == 0) red[w * 39 + c] = v;
            v = wave_sum(z0v[c]); if (lane == 0) red[w * 39 + 3 + c] = v;
            v = wave_sum(z1v[c]); if (lane == 0) red[w * 39 + 6 + c] = v;
            v = wave_sum(z2v[c]); if (lane == 0) red[w * 39 + 9 + c] = v;
            v = wave_sum(d4v[c]); if (lane == 0) red[w * 39 + 12 + c] = v;
#pragma unroll
            for (int k = 4; k < 12; ++k) {
                unsigned sb = ((Wt >> (11 - k)) & 1u) << 31;
                v = wave_sum(fflip(d4v[c], sb));
                if (lane == 0) red[w * 39 + 3 + 3 * k + c] = v;
            }
        }
    }
    __syncthreads();
    if (t < 66) {
        int c = t % 3, q = t / 3;
        int slot = (q == 0 || q == 21) ? (3 + 33 + c) : (q < 10 ? c : 3 + 3 * (q - 10) + c);
        float val = red[slot] + red[39 + slot] + red[78 + slot] + red[117 + slot];
        unsigned sg = (unsigned)__popc(base & M.zrow[q]) & 1u;
        atomicAdd(&acc[4 * NQ + 3 * q + c], sg ? -val : val);
    }
    __syncthreads();

    // ---- measurements q10..q20 (masks within bits 0..11), vectorized from LDS ----
    int lane = t & 63, w = t >> 6;
    for (int i = 0; i < 11; ++i) {
        unsigned m = M.xm[i], zm = M.zm[i];
        unsigned zb = (unsigned)__popc(base & zm) & 1u;
        float t00 = 0.f, t11 = 0.f, t01 = 0.f, u01 = 0.f;
        if (i < 10) {
            int gb = M.gbit[i];
            unsigned mg4 = m >> 2;
            unsigned swap2 = m & 3u;            // 0 or 2
#pragma unroll
            for (int r = 0; r < 2; ++r) {
                unsigned gc = (unsigned)t + 256u * r;
                unsigned g = ((gc >> gb) << (gb + 1)) | (gc & ((1u << gb) - 1u));
                unsigned gx = g ^ mg4;
                float4 a0 = As4[ph4(g)],  a1 = Bs4[ph4(g)];
                float4 b0 = As4[ph4(gx)], b1 = Bs4[ph4(gx)];
                if (swap2) {
                    b0 = make_float4(b0.z, b0.w, b0.x, b0.y);
                    b1 = make_float4(b1.z, b1.w, b1.x, b1.y);
                }
                unsigned szg = ((unsigned)__popc((g << 2) & zm) + zb) & 1u;
                unsigned szx = ((unsigned)__popc((gx << 2) & zm) + zb) & 1u;
                unsigned fg = szg << 31, fx = szx << 31;
                const float* A0 = &a0.x; const float* A1 = &a1.x;
                const float* B0 = &b0.x; const float* B1 = &b1.x;
#pragma unroll
                for (int j = 0; j < 4; ++j) {
                    t00 += A0[j] * B0[j];
                    t11 += A1[j] * B1[j];
                    float p = A0[j] * B1[j], r2 = B0[j] * A1[j];
                    t01 += p + r2;
                    u01 += fflip(p, fx) + fflip(r2, fg);
                }
            }
            t00 *= 2.f; t11 *= 2.f;
        } else {
            // q20: m = 3, partner within float4
#pragma unroll
            for (int k = 0; k < 4; ++k) {
                unsigned g = (unsigned)t + 256u * k;
                float4 a0 = As4[ph4(g)], a1 = Bs4[ph4(g)];
                unsigned szg = ((unsigned)__popc((g << 2) & zm) + zb) & 1u;
                const float* A0 = &a0.x; const float* A1 = &a1.x;
#pragma unroll
                for (int j = 0; j < 4; ++j) {
                    int jx = j ^ 3;
                    float p = A0[j] * A0[jx];
                    float q2 = A1[j] * A1[jx];
                    float cr = A0[j] * A1[jx];
                    t00 += p; t11 += q2; t01 += cr;
                    unsigned sj = ((unsigned)(jx >> 1) & 1u) ^ szg;   // zm&3 == 2
                    u01 += fflip(cr, sj << 31);
                }
            }
        }
        float vals[4] = { t00, t11, t01, u01 };
#pragma unroll
        for (int j = 0; j < 4; ++j) {
            float v = wave_sum(vals[j]);
            if (lane == 0) red[w * 44 + 4 * i + j] = v;
        }
    }
    __syncthreads();
    if (t < 44) {
        float r = red[t] + red[44 + t] + red[88 + t] + red[132 + t];
        atomicAdd(&acc[40 + t], r);
    }
}

// ------- slice X/Y measurements for q0, q7, q8, q9, q21 — grid (256, 5) -----------
__global__ __launch_bounds__(256) void k_measS(const float* __restrict__ phi,
                                               float* __restrict__ acc,
                                               Meas5Arg M) {
    __shared__ float red[16];
    int t = threadIdx.x;
    int slice = blockIdx.y;
    unsigned m = M.xm[slice], zm = M.zm[slice];
    int gb = M.gbit[slice];
    unsigned mg4 = m >> 2;
    unsigned ml2 = m & 3u;                      // 0 or 1
    unsigned zl = zm & 3u;
    unsigned pg31[4], px31[4];
#pragma unroll
    for (int j = 0; j < 4; ++j) {
        pg31[j] = (((unsigned)__popc((unsigned)j & zl) & 1u) << 31);
        px31[j] = (((unsigned)__popc(((unsigned)j ^ ml2) & zl) & 1u) << 31);
    }
    unsigned tid = blockIdx.x * 256u + (unsigned)t;   // [0, 65536)
    const float4* p0 = (const float4*)phi;
    const float4* p1 = (const float4*)(phi + DIMN);
    float t00 = 0.f, t11 = 0.f, t01 = 0.f, u01 = 0.f;
#pragma unroll
    for (int it = 0; it < 8; ++it) {
        unsigned gc = tid + (unsigned)it * 65536u;    // [0, 2^19)
        unsigned g = ((gc >> gb) << (gb + 1)) | (gc & ((1u << gb) - 1u));
        unsigned gx = g ^ mg4;
        float4 a0 = p0[g], a1 = p1[g];
        float4 b0 = p0[gx], b1 = p1[gx];
        if (ml2) {
            b0 = make_float4(b0.y, b0.x, b0.w, b0.z);
            b1 = make_float4(b1.y, b1.x, b1.w, b1.z);
        }
        unsigned fg = (((unsigned)__popc((g << 2) & zm) & 1u) << 31);
        unsigned fx = (((unsigned)__popc((gx << 2) & zm) & 1u) << 31);
        const float* A0 = &a0.x; const float* A1 = &a1.x;
        const float* B0 = &b0.x; const float* B1 = &b1.x;
#pragma unroll
        for (int j = 0; j < 4; ++j) {
            t00 += A0[j] * B0[j];
            t11 += A1[j] * B1[j];
            float p = A0[j] * B1[j], r = B0[j] * A1[j];
            t01 += p + r;
            u01 += fflip(p, fx ^ px31[j]) + fflip(r, fg ^ pg31[j]);
        }
    }
    t00 *= 2.f; t11 *= 2.f;
    int lane = t & 63, w = t >> 6;
    float vals[4] = { t00, t11, t01, u01 };
#pragma unroll
    for (int j = 0; j < 4; ++j) {
        float v = wave_sum(vals[j]);
        if (lane == 0) red[w * 4 + j] = v;
    }
    __syncthreads();
    if (t < 4) {
        float r = red[t] + red[4 + t] + red[8 + t] + red[12 + t];
        atomicAdd(&acc[4 * M.qn[slice] + t], r);
    }
}

// ---------------- finalize: combine 154 sums into the scalar loss ----------------
__global__ __launch_bounds__(64) void k_final(const float* __restrict__ acc,
                                              float* __restrict__ out) {
    int t = threadIdx.x;
    float v = 0.f;
    if (t < NQ) {
        float t00 = acc[4 * t], t11 = acc[4 * t + 1];
        float t01 = acc[4 * t + 2], u01 = acc[4 * t + 3];
        float d = t00 - t11;
        v = 0.5f * d * d + 2.f * t01 * t01 + 2.f * u01 * u01;   // X op + Y op
    } else if (t < 2 * NQ) {
        int q = t - NQ;
        float z0 = acc[4 * NQ + 3 * q], z1 = acc[4 * NQ + 3 * q + 1];
        float zz = acc[4 * NQ + 3 * q + 2];
        float d = z0 - z1;
        v = 0.5f * d * d + 2.f * zz * zz;                       // Z op
    }
    v += __shfl_down(v, 32); v += __shfl_down(v, 16); v += __shfl_down(v, 8);
    v += __shfl_down(v, 4);  v += __shfl_down(v, 2);  v += __shfl_down(v, 1);
    if (t == 0) out[0] = v;
}

extern "C" void kernel_launch(void* const* d_in, const int* in_sizes, int n_in,
                              void* d_out, int out_size, void* d_ws, size_t ws_size,
                              hipStream_t stream) {
    const float* theta = (const float*)d_in[0];
    float* out  = (float*)d_out;
    float* ws   = (float*)d_ws;
    float* phi  = ws;                          // 2 * DIMN floats (32 MB)
    float* acc  = ws + 2 * (size_t)DIMN;       // 256 floats
    float* trig = acc + 256;                   // 88 floats

    // Build L (one CNOT ring layer over GF(2)); qubit q lives at bit (21-q).
    unsigned L[NQ];
    for (int b = 0; b < NQ; ++b) L[b] = 1u << b;
    for (int q = 0; q < NQ; ++q) {
        int bc = NQ - 1 - q;
        int bt = NQ - 1 - ((q + 1) % NQ);
        L[bt] ^= L[bc];
    }
    // Invert over GF(2): x_b = parity(y & Linv[b])
    unsigned mat[NQ], aug[NQ];
    for (int b = 0; b < NQ; ++b) { mat[b] = L[b]; aug[b] = 1u << b; }
    for (int col = 0; col < NQ; ++col) {
        int piv = col;
        while (!((mat[piv] >> col) & 1u)) ++piv;
        unsigned tm = mat[piv]; mat[piv] = mat[col]; mat[col] = tm;
        unsigned ta = aug[piv]; aug[piv] = aug[col]; aug[col] = ta;
        for (int r = 0; r < NQ; ++r)
            if (r != col && ((mat[r] >> col) & 1u)) { mat[r] ^= mat[col]; aug[r] ^= aug[col]; }
    }
    GenArg ga;
    for (int b = 0; b < NQ; ++b) ga.r[b] = aug[b];
    for (int j = 0; j < 5; ++j) {
        unsigned f = 0;
        for (int r = 0; r < NQ; ++r)
            if ((aug[r] >> (12 + j)) & 1u) f |= 1u << r;
        ga.frow[j] = f;
    }

    // Conjugated Pauli masks: X_q -> X^(col 21-q of Linv); Z_q -> Z^(row 21-q of L)
    unsigned xmask[NQ], zmask[NQ];
    for (int j = 0; j < NQ; ++j) {
        int b = NQ - 1 - j;
        unsigned xm = 0;
        for (int r = 0; r < NQ; ++r)
            if ((aug[r] >> b) & 1u) xm |= 1u << r;
        xmask[j] = xm;          // q0..9: {21-j,20-j}; q10..20: low pairs; q21: {0,20,21}
        zmask[j] = L[b];        // suffix masks; q0: {0..20}; q21: {0..21}
    }
    auto topbit = [](unsigned v) { int b = 0; while (v >> (b + 1)) ++b; return b; };

    // k_hiM masks: q1..q6 (xmask within bits 14..21, zmask within bits >= 14)
    HiMArg hm;
    for (int i = 0; i < 6; ++i) {
        int q = 1 + i;
        hm.he[i]  = (xmask[q] >> 17) & 31u;
        hm.hm[i]  = (xmask[q] >> 14) & 7u;
        hm.zme[i] = (zmask[q] >> 17) & 31u;
        hm.zmm[i] = (zmask[q] >> 14) & 7u;
    }

    MeasLArg ml;
    for (int i = 0; i < 11; ++i) {
        int q = 10 + i;
        ml.xm[i] = xmask[q]; ml.zm[i] = zmask[q];
        ml.gbit[i] = topbit(xmask[q]) - 2;     // q10..19 (q20 special-cased)
    }
    for (int q = 0; q < NQ; ++q) ml.zrow[q] = zmask[q];

    // slice masks: q0, q7, q8, q9, q21
    Meas5Arg m5;
    const int qs[5] = { 0, 7, 8, 9, 21 };
    for (int i = 0; i < 5; ++i) {
        int q = qs[i];
        m5.xm[i] = xmask[q]; m5.zm[i] = zmask[q];
        m5.gbit[i] = topbit(xmask[q]) - 2;
        m5.qn[i] = q;
    }

    k_prep<<<1, 256, 0, stream>>>(theta, acc, trig);
    k_gen<<<512, 256, 0, stream>>>(phi, trig, ga);
    k_hiM<<<256, 512, 0, stream>>>(phi, trig, acc, hm);
    k_low<<<1024, 256, 0, stream>>>(phi, trig, acc, ml);
    k_measS<<<dim3(256, 5), 256, 0, stream>>>(phi, acc, m5);
    k_final<<<1, 64, 0, stream>>>(acc, out);
}